// Round 8
// baseline (171.131 us; speedup 1.0000x reference)
//
#include <hip/hip_runtime.h>

#define B_DIM 8192
#define H_DIM 1024
#define K_DIM 2048   // I + H
#define N_DIM 4096   // 4H
#define BH (B_DIM * H_DIM)
#define NT 32                // K-tiles (BK=64)
#define BTSZ (256 * 64)      // elems per B LDS buffer (32 KB)
#define HALFB (128 * 64)     // elems per half of B tile

using frag_ab = __attribute__((ext_vector_type(8))) short;   // 8 bf16
using frag_cd = __attribute__((ext_vector_type(4))) float;
using short8 = __attribute__((ext_vector_type(8))) short;

__device__ __forceinline__ unsigned short f2bf(float f) {
  union { float f; unsigned u; } x; x.f = f;
  return (unsigned short)((x.u + 0x7fffu + ((x.u >> 16) & 1u)) >> 16);
}

// ---- pack [xt | hx] -> bf16 A in FRAGMENT-TILED layout ----
// A_t[mt][kt][l][8]: element = A[mt*16 + (l&15)][kt*32 + (l>>4)*8 + j]
// One MFMA A-fragment (16x32) = 1 KB contiguous, lane l reads bytes l*16..+15.
__global__ __launch_bounds__(256) void convert_A_kernel(
    const float* __restrict__ xt, const float* __restrict__ hx,
    unsigned short* __restrict__ At) {
  int g = blockIdx.x * 256 + threadIdx.x;       // [0, 512*64*64)
  int mt = g >> 12;
  int kt = (g >> 6) & 63;
  int l = g & 63;
  int row = mt * 16 + (l & 15);
  int col = kt * 32 + (l >> 4) * 8;
  const float* src = (col < 1024) ? (xt + (size_t)row * 1024 + col)
                                  : (hx + (size_t)row * 1024 + (col - 1024));
  float4 v0 = *reinterpret_cast<const float4*>(src);
  float4 v1 = *reinterpret_cast<const float4*>(src + 4);
  short8 o;
  o[0] = f2bf(v0.x); o[1] = f2bf(v0.y); o[2] = f2bf(v0.z); o[3] = f2bf(v0.w);
  o[4] = f2bf(v1.x); o[5] = f2bf(v1.y); o[6] = f2bf(v1.z); o[7] = f2bf(v1.w);
  *reinterpret_cast<short8*>(At + (size_t)g * 8) = o;
}

// ---- pack gate-interleaved [W | R] -> bf16 B[4096][2048] ----
// output row n: tile=n>>8, c=n&255 -> gate=(c>>4)&3, h=tile*64+(c>>6)*16+(c&15)
__global__ __launch_bounds__(256) void convert_B_kernel(
    const float* __restrict__ w0, const float* __restrict__ w1,
    const float* __restrict__ w2, const float* __restrict__ w3,
    const float* __restrict__ r0, const float* __restrict__ r1,
    const float* __restrict__ r2, const float* __restrict__ r3,
    unsigned short* __restrict__ Bb) {
  int tid = blockIdx.x * 256 + threadIdx.x;
  int flat = tid * 4;
  int n = flat >> 11;
  int k = flat & 2047;
  int tile = n >> 8, c = n & 255;
  int gate = (c >> 4) & 3;
  int h = tile * 64 + ((c >> 6) << 4) + (c & 15);
  const float* wb = (gate == 0) ? w0 : (gate == 1) ? w1 : (gate == 2) ? w2 : w3;
  const float* rb = (gate == 0) ? r0 : (gate == 1) ? r1 : (gate == 2) ? r2 : r3;
  const float* src = (k < 1024) ? (wb + h * 1024 + k)
                                : (rb + h * 1024 + (k - 1024));
  float4 v = *reinterpret_cast<const float4*>(src);
  ushort4 o;
  o.x = f2bf(v.x); o.y = f2bf(v.y); o.z = f2bf(v.z); o.w = f2bf(v.w);
  *reinterpret_cast<ushort4*>(Bb + flat) = o;
}

__device__ __forceinline__ void gload_lds16(const void* g, void* l) {
  __builtin_amdgcn_global_load_lds(
      (const __attribute__((address_space(1))) unsigned int*)g,
      (__attribute__((address_space(3))) unsigned int*)l, 16, 0, 0);
}

__device__ __forceinline__ frag_ab ldsr(const unsigned short* buf, int byteoff) {
  return *reinterpret_cast<const frag_ab*>(
      reinterpret_cast<const char*>(buf) + byteoff);
}

__device__ __forceinline__ float fast_sigmoid(float x) {
  return 1.f / (1.f + __expf(-x));
}
__device__ __forceinline__ float fast_tanh(float x) {
  return 1.f - 2.f / (__expf(2.f * x) + 1.f);
}

#define CBAR asm volatile("" ::: "memory")
#define SBAR do { CBAR; __builtin_amdgcn_s_barrier(); CBAR; } while (0)
#define SCHED0 __builtin_amdgcn_sched_barrier(0)

// One K-tile, ONE barrier. B staged to LDS (double-buffered); A fragments
// loaded straight from global (fragment-tiled layout) into VGPRs, quadrant
// pipelined (issue Q+1's 4 loads, MFMA Q's frags; compiler tracks reg deps
// with precise vmcnt). Manual vmcnt(16) at tile end drains the 4 B-stage
// loads (pinned oldest by sched_barrier) while 16 A-loads stay in flight.
#define TILE_BODY(Bc, Bn, tt, S, P, VMQ)                                       \
  {                                                                            \
    if (S) {                                                                   \
      stage(Bg + (size_t)((tt) + 1) * 64, (Bn));                               \
      stage(Bg + (size_t)((tt) + 1) * 64 + 128 * K_DIM, (Bn) + HALFB);         \
    }                                                                          \
    SCHED0;  /* pin B-stage as oldest VMEM of the tile */                      \
    _Pragma("unroll") for (int n = 0; n < 4; ++n) {                            \
      Bf[n][0] = ldsr(Bc, (brow + n * 16) * 128 + c0);                         \
      Bf[n][1] = ldsr(Bc, (brow + n * 16) * 128 + c1);                         \
    }                                                                          \
    /* Q0: MFMA m0-3 kk0 (Af0 preloaded); issue Af1 <- m0-3 kk1 */             \
    _Pragma("unroll") for (int m = 0; m < 4; ++m)                              \
        Af1[m] = *reinterpret_cast<const frag_ab*>(                            \
            awave + (size_t)m * 32768 + (2 * (tt) + 1) * 512);                 \
    __builtin_amdgcn_s_setprio(1);                                             \
    _Pragma("unroll") for (int m = 0; m < 4; ++m)                              \
        _Pragma("unroll") for (int n = 0; n < 4; ++n)                          \
            acc[m][n] = __builtin_amdgcn_mfma_f32_16x16x32_bf16(               \
                Af0[m], Bf[n][0], acc[m][n], 0, 0, 0);                         \
    __builtin_amdgcn_s_setprio(0);                                             \
    /* Q1: issue Af0 <- m4-7 kk0; MFMA m0-3 kk1 */                             \
    _Pragma("unroll") for (int m = 0; m < 4; ++m)                              \
        Af0[m] = *reinterpret_cast<const frag_ab*>(                            \
            awave + (size_t)(4 + m) * 32768 + (2 * (tt)) * 512);               \
    __builtin_amdgcn_s_setprio(1);                                             \
    _Pragma("unroll") for (int m = 0; m < 4; ++m)                              \
        _Pragma("unroll") for (int n = 0; n < 4; ++n)                          \
            acc[m][n] = __builtin_amdgcn_mfma_f32_16x16x32_bf16(               \
                Af1[m], Bf[n][1], acc[m][n], 0, 0, 0);                         \
    __builtin_amdgcn_s_setprio(0);                                             \
    /* Q2: issue Af1 <- m4-7 kk1; MFMA m4-7 kk0 */                             \
    _Pragma("unroll") for (int m = 0; m < 4; ++m)                              \
        Af1[m] = *reinterpret_cast<const frag_ab*>(                            \
            awave + (size_t)(4 + m) * 32768 + (2 * (tt) + 1) * 512);           \
    __builtin_amdgcn_s_setprio(1);                                             \
    _Pragma("unroll") for (int m = 0; m < 4; ++m)                              \
        _Pragma("unroll") for (int n = 0; n < 4; ++n)                          \
            acc[4 + m][n] = __builtin_amdgcn_mfma_f32_16x16x32_bf16(           \
                Af0[m], Bf[n][0], acc[4 + m][n], 0, 0, 0);                     \
    __builtin_amdgcn_s_setprio(0);                                             \
    /* Q3: issue Af0 <- m0-3 kk0 of tile t+1; MFMA m4-7 kk1 */                 \
    if (P) _Pragma("unroll") for (int m = 0; m < 4; ++m)                       \
        Af0[m] = *reinterpret_cast<const frag_ab*>(                            \
            awave + (size_t)m * 32768 + (2 * (tt) + 2) * 512);                 \
    __builtin_amdgcn_s_setprio(1);                                             \
    _Pragma("unroll") for (int m = 0; m < 4; ++m)                              \
        _Pragma("unroll") for (int n = 0; n < 4; ++n)                          \
            acc[4 + m][n] = __builtin_amdgcn_mfma_f32_16x16x32_bf16(           \
                Af1[m], Bf[n][1], acc[4 + m][n], 0, 0, 0);                     \
    __builtin_amdgcn_s_setprio(0);                                             \
    if (VMQ) {                                                                 \
      asm volatile("s_waitcnt vmcnt(16)" ::: "memory");  /* B-stage landed */  \
      SBAR;                                                                    \
    }                                                                          \
  }

// ---- 256x256 GEMM: A direct-from-global (tiled), B LDS-staged, 1 bar/tile --
__global__ __launch_bounds__(512, 2) void lstm_gemm_kernel(
    const unsigned short* __restrict__ At,   // fragment-tiled A
    const unsigned short* __restrict__ Bb,   // [4096][2048] bf16, gate-permuted
    const float* __restrict__ cx,
    const float* __restrict__ b_f, const float* __restrict__ b_i,
    const float* __restrict__ b_o, const float* __restrict__ b_g,
    float* __restrict__ out) {
  extern __shared__ unsigned short smem[];   // 64 KiB: B double buffer
  unsigned short* const Bs0 = smem;
  unsigned short* const Bs1 = smem + BTSZ;

  const int bid = blockIdx.x;
  const int swz = (bid & 7) * 64 + (bid >> 3);    // 512 wgs % 8 == 0: bijective
  const int bm = swz >> 4;                        // 32 M-tiles
  const int bn = swz & 15;                        // 16 N-tiles

  const int tid = threadIdx.x;
  const int lane = tid & 63;
  const int wid = tid >> 6;
  const int wr = wid >> 2, wc = wid & 3;          // 2x4 waves, 128x64 each
  const int ln = lane & 15, kh = lane >> 4;

  // per-wave A fragment base: mt = bm*16 + wr*8 + m, frag = 1 KB
  const unsigned short* awave =
      At + ((size_t)(bm * 16 + wr * 8) * 64) * 512 + lane * 8;
  const unsigned short* Bg = Bb + (size_t)(bn * 256) * K_DIM;

  // B-stage invariants: wave covers 16 rows of a 128-row half (2 gloads)
  const size_t gs0 = (size_t)(wid * 16 + (lane >> 3)) * K_DIM +
                     (((lane & 7) ^ (lane >> 3)) << 3);
  const size_t gs1 = gs0 + (size_t)8 * K_DIM;
  const int ld0 = wid * 2048 + lane * 16;         // LDS byte offsets (linear)
  const int ld1 = ld0 + 1024;
  auto stage = [&](const unsigned short* g, unsigned short* l) {
    gload_lds16(g + gs0, reinterpret_cast<char*>(l) + ld0);
    gload_lds16(g + gs1, reinterpret_cast<char*>(l) + ld1);
  };

  // B read invariants (byte offsets; XOR swizzle with loop-invariant key)
  const int inv = (ln & 7) << 4;
  const int c0 = (kh * 16) ^ inv;                 // kk0 column
  const int c1 = (64 + kh * 16) ^ inv;            // kk1 column
  const int brow = wc * 64 + ln;

  frag_cd acc[8][4] = {};
  frag_ab Af0[4], Af1[4], Bf[4][2];

  // ---- prologue: stage B(0); preload A Q0(0); drain B(0) ----
  stage(Bg, Bs0);
  stage(Bg + 128 * K_DIM, Bs0 + HALFB);
#pragma unroll
  for (int m = 0; m < 4; ++m)
    Af0[m] = *reinterpret_cast<const frag_ab*>(awave + (size_t)m * 32768);
  asm volatile("s_waitcnt vmcnt(4)" ::: "memory");
  SBAR;

  // ---- main loop: 2 K-tiles per iter, static buffers ----
  for (int u = 0; u < 15; ++u) {
    const int e = 2 * u;
    TILE_BODY(Bs0, Bs1, e, 1, 1, 1);
    TILE_BODY(Bs1, Bs0, e + 1, 1, 1, 1);
  }
  // t=30: stage B(31), prefetch A(31)Q0, drain
  TILE_BODY(Bs0, Bs1, 30, 1, 1, 1);
  // t=31: pure compute, internal A pipelining only
  TILE_BODY(Bs1, Bs0, 31, 0, 0, 0);

  // ---- fused LSTM epilogue: n-frag == gate, h = bn*64 + wc*16 + ln ----
  const int hcol = bn * 64 + wc * 16 + ln;
  const float bfv = b_f[hcol], biv = b_i[hcol], bov = b_o[hcol], bgv = b_g[hcol];
  const int row_base = bm * 256 + wr * 128 + kh * 4;
#pragma unroll
  for (int mi = 0; mi < 8; ++mi) {
#pragma unroll
    for (int j = 0; j < 4; ++j) {
      const int row = row_base + mi * 16 + j;
      float fp = acc[mi][0][j] + bfv;
      float ip = acc[mi][1][j] + biv;
      float op = acc[mi][2][j] + bov;
      float gp = acc[mi][3][j] + bgv;
      float ft = fast_sigmoid(fp);
      float it = fast_sigmoid(ip);
      float ot = fast_sigmoid(op);
      float gt = fast_tanh(gp);
      float cold = cx[(size_t)row * H_DIM + hcol];
      float ct = ft * cold + it * gt;
      float ht = ot * fast_tanh(ct);
      out[(size_t)row * H_DIM + hcol] = ht;
      out[BH + (size_t)row * H_DIM + hcol] = ct;
    }
  }
}

extern "C" void kernel_launch(void* const* d_in, const int* in_sizes, int n_in,
                              void* d_out, int out_size, void* d_ws, size_t ws_size,
                              hipStream_t stream) {
  const float* xt   = (const float*)d_in[0];
  const float* cxp  = (const float*)d_in[1];
  const float* hx   = (const float*)d_in[2];
  const float* w_fg = (const float*)d_in[3];
  const float* w_ig = (const float*)d_in[4];
  const float* w_og = (const float*)d_in[5];
  const float* w_ci = (const float*)d_in[6];
  const float* r_fg = (const float*)d_in[7];
  const float* r_ig = (const float*)d_in[8];
  const float* r_og = (const float*)d_in[9];
  const float* r_ci = (const float*)d_in[10];
  const float* b_fg = (const float*)d_in[11];
  const float* b_ig = (const float*)d_in[12];
  const float* b_og = (const float*)d_in[13];
  const float* b_ci = (const float*)d_in[14];

  unsigned short* Atf = (unsigned short*)d_ws;                // 33.5 MB tiled A
  unsigned short* Bbf = Atf + (size_t)B_DIM * K_DIM;          // 16.8 MB
  float* out = (float*)d_out;

  convert_A_kernel<<<dim3(B_DIM * K_DIM / 8 / 256), dim3(256), 0, stream>>>(
      xt, hx, Atf);
  convert_B_kernel<<<dim3(N_DIM * K_DIM / 4 / 256), dim3(256), 0, stream>>>(
      w_fg, w_ig, w_og, w_ci, r_fg, r_ig, r_og, r_ci, Bbf);
  lstm_gemm_kernel<<<dim3((B_DIM / 256) * (N_DIM / 256)), dim3(512),
                     65536, stream>>>(
      Atf, Bbf, cxp, b_fg, b_ig, b_og, b_ci, out);
}

// Round 9
// 159.510 us; speedup vs baseline: 1.0729x; 1.0729x over previous
//
#include <hip/hip_runtime.h>

#define B_DIM 8192
#define H_DIM 1024
#define K_DIM 2048   // I + H
#define N_DIM 4096   // 4H
#define BH (B_DIM * H_DIM)
#define NT 32                // K-tiles (BK=64)
#define TSZ (256 * 64)       // elems per LDS tile buffer (32 KB)
#define HALFT (128 * 64)     // elems per half-tile

using frag_ab = __attribute__((ext_vector_type(8))) short;   // 8 bf16
using frag_cd = __attribute__((ext_vector_type(4))) float;

__device__ __forceinline__ unsigned short f2bf(float f) {
  union { float f; unsigned u; } x; x.f = f;
  return (unsigned short)((x.u + 0x7fffu + ((x.u >> 16) & 1u)) >> 16);
}

// ---- pack [xt | hx] -> bf16 A[8192][2048] ----
__global__ __launch_bounds__(256) void convert_A_kernel(
    const float* __restrict__ xt, const float* __restrict__ hx,
    unsigned short* __restrict__ Ab) {
  int tid = blockIdx.x * 256 + threadIdx.x;
  int flat = tid * 4;
  int m = flat >> 11;
  int k = flat & 2047;
  const float* src = (k < 1024) ? (xt + m * 1024 + k)
                                : (hx + m * 1024 + (k - 1024));
  float4 v = *reinterpret_cast<const float4*>(src);
  ushort4 o;
  o.x = f2bf(v.x); o.y = f2bf(v.y); o.z = f2bf(v.z); o.w = f2bf(v.w);
  *reinterpret_cast<ushort4*>(Ab + flat) = o;
}

// ---- pack gate-interleaved [W | R] -> bf16 B[4096][2048] ----
// output row n: tile=n>>8, c=n&255 -> gate=(c>>4)&3, h=tile*64+(c>>6)*16+(c&15)
__global__ __launch_bounds__(256) void convert_B_kernel(
    const float* __restrict__ w0, const float* __restrict__ w1,
    const float* __restrict__ w2, const float* __restrict__ w3,
    const float* __restrict__ r0, const float* __restrict__ r1,
    const float* __restrict__ r2, const float* __restrict__ r3,
    unsigned short* __restrict__ Bb) {
  int tid = blockIdx.x * 256 + threadIdx.x;
  int flat = tid * 4;
  int n = flat >> 11;
  int k = flat & 2047;
  int tile = n >> 8, c = n & 255;
  int gate = (c >> 4) & 3;
  int h = tile * 64 + ((c >> 6) << 4) + (c & 15);
  const float* wb = (gate == 0) ? w0 : (gate == 1) ? w1 : (gate == 2) ? w2 : w3;
  const float* rb = (gate == 0) ? r0 : (gate == 1) ? r1 : (gate == 2) ? r2 : r3;
  const float* src = (k < 1024) ? (wb + h * 1024 + k)
                                : (rb + h * 1024 + (k - 1024));
  float4 v = *reinterpret_cast<const float4*>(src);
  ushort4 o;
  o.x = f2bf(v.x); o.y = f2bf(v.y); o.z = f2bf(v.z); o.w = f2bf(v.w);
  *reinterpret_cast<ushort4*>(Bb + flat) = o;
}

__device__ __forceinline__ void gload_lds16(const void* g, void* l) {
  __builtin_amdgcn_global_load_lds(
      (const __attribute__((address_space(1))) unsigned int*)g,
      (__attribute__((address_space(3))) unsigned int*)l, 16, 0, 0);
}

__device__ __forceinline__ frag_ab ldsr(const unsigned short* buf, int byteoff) {
  return *reinterpret_cast<const frag_ab*>(
      reinterpret_cast<const char*>(buf) + byteoff);
}

__device__ __forceinline__ float fast_sigmoid(float x) {
  return 1.f / (1.f + __expf(-x));
}
__device__ __forceinline__ float fast_tanh(float x) {
  return 1.f - 2.f / (__expf(2.f * x) + 1.f);
}

#define CBAR asm volatile("" ::: "memory")
#define SBAR do { CBAR; __builtin_amdgcn_s_barrier(); CBAR; } while (0)

// ONE barrier per K-tile. Stage A(t+1),B(t+1) first (whole tile to land),
// then four {ds_reads -> 16 MFMA} chunks with NO barriers or asm waits inside:
// compiler-emitted fine-grained lgkmcnt lets chunk i+1's reads run in the LDS
// pipe underneath chunk i's MFMA issue-block, and the 2 waves/SIMD stagger.
// Ledger: stage victims (other ping-pong buffer) were last read in tile t-1,
// retired by the tile-(t-1) barrier. vmcnt(0)+barrier at tile end publishes.
#define TILE_BODY(Ac, Bc, An, Bn, tt, S, ENDBAR)                               \
  {                                                                            \
    if (S) {                                                                   \
      stage(Ag + (size_t)((tt) + 1) * 64, (An));                               \
      stage(Ag + (size_t)((tt) + 1) * 64 + 128 * K_DIM, (An) + HALFT);         \
      stage(Bg + (size_t)((tt) + 1) * 64, (Bn));                               \
      stage(Bg + (size_t)((tt) + 1) * 64 + 128 * K_DIM, (Bn) + HALFT);         \
    }                                                                          \
    /* ---- Q0: reads kk0 (A m0-3, B n0-3); MFMA ---- */                       \
    _Pragma("unroll") for (int m = 0; m < 4; ++m)                              \
        Af0[m] = ldsr(Ac, (arow + m * 16) * 128 + c0);                         \
    _Pragma("unroll") for (int n = 0; n < 4; ++n)                              \
        Bf0[n] = ldsr(Bc, (brow + n * 16) * 128 + c0);                         \
    __builtin_amdgcn_s_setprio(1);                                             \
    _Pragma("unroll") for (int m = 0; m < 4; ++m)                              \
        _Pragma("unroll") for (int n = 0; n < 4; ++n)                          \
            acc[m][n] = __builtin_amdgcn_mfma_f32_16x16x32_bf16(               \
                Af0[m], Bf0[n], acc[m][n], 0, 0, 0);                           \
    __builtin_amdgcn_s_setprio(0);                                             \
    /* ---- Q1: reads kk1 (A m0-3, B n0-3); MFMA ---- */                       \
    _Pragma("unroll") for (int m = 0; m < 4; ++m)                              \
        Af1[m] = ldsr(Ac, (arow + m * 16) * 128 + c1);                         \
    _Pragma("unroll") for (int n = 0; n < 4; ++n)                              \
        Bf1[n] = ldsr(Bc, (brow + n * 16) * 128 + c1);                         \
    __builtin_amdgcn_s_setprio(1);                                             \
    _Pragma("unroll") for (int m = 0; m < 4; ++m)                              \
        _Pragma("unroll") for (int n = 0; n < 4; ++n)                          \
            acc[m][n] = __builtin_amdgcn_mfma_f32_16x16x32_bf16(               \
                Af1[m], Bf1[n], acc[m][n], 0, 0, 0);                           \
    __builtin_amdgcn_s_setprio(0);                                             \
    /* ---- Q2: reads A m4-7 kk0 (Bf0 held); MFMA ---- */                      \
    _Pragma("unroll") for (int m = 0; m < 4; ++m)                              \
        Af0[m] = ldsr(Ac, (arow + 64 + m * 16) * 128 + c0);                    \
    __builtin_amdgcn_s_setprio(1);                                             \
    _Pragma("unroll") for (int m = 0; m < 4; ++m)                              \
        _Pragma("unroll") for (int n = 0; n < 4; ++n)                          \
            acc[4 + m][n] = __builtin_amdgcn_mfma_f32_16x16x32_bf16(           \
                Af0[m], Bf0[n], acc[4 + m][n], 0, 0, 0);                       \
    __builtin_amdgcn_s_setprio(0);                                             \
    /* ---- Q3: reads A m4-7 kk1 (Bf1 held); MFMA ---- */                      \
    _Pragma("unroll") for (int m = 0; m < 4; ++m)                              \
        Af1[m] = ldsr(Ac, (arow + 64 + m * 16) * 128 + c1);                    \
    __builtin_amdgcn_s_setprio(1);                                             \
    _Pragma("unroll") for (int m = 0; m < 4; ++m)                              \
        _Pragma("unroll") for (int n = 0; n < 4; ++n)                          \
            acc[4 + m][n] = __builtin_amdgcn_mfma_f32_16x16x32_bf16(           \
                Af1[m], Bf1[n], acc[4 + m][n], 0, 0, 0);                       \
    __builtin_amdgcn_s_setprio(0);                                             \
    if (S) asm volatile("s_waitcnt vmcnt(0)" ::: "memory");                    \
    if (ENDBAR) SBAR;                                                          \
  }

// ---- 256x256 tile GEMM, 1 barrier per K-tile, fused LSTM epilogue ----
__global__ __launch_bounds__(512, 2) void lstm_gemm_kernel(
    const unsigned short* __restrict__ Ab,   // [8192][2048] bf16
    const unsigned short* __restrict__ Bb,   // [4096][2048] bf16, gate-permuted
    const float* __restrict__ cx,
    const float* __restrict__ b_f, const float* __restrict__ b_i,
    const float* __restrict__ b_o, const float* __restrict__ b_g,
    float* __restrict__ out) {
  extern __shared__ unsigned short smem[];   // 128 KiB
  unsigned short* const As0 = smem;
  unsigned short* const As1 = smem + TSZ;
  unsigned short* const Bs0 = smem + 2 * TSZ;
  unsigned short* const Bs1 = smem + 3 * TSZ;

  const int bid = blockIdx.x;
  const int swz = (bid & 7) * 64 + (bid >> 3);    // 512 wgs % 8 == 0: bijective
  const int bm = swz >> 4;                        // 32 M-tiles
  const int bn = swz & 15;                        // 16 N-tiles

  const int tid = threadIdx.x;
  const int lane = tid & 63;
  const int wid = tid >> 6;
  const int wr = wid >> 2, wc = wid & 3;          // 2x4 waves, 128x64 each
  const int ln = lane & 15, kh = lane >> 4;

  const unsigned short* Ag = Ab + (size_t)(bm * 256) * K_DIM;
  const unsigned short* Bg = Bb + (size_t)(bn * 256) * K_DIM;

  // stage invariants: wave covers 16 rows of a 128-row half (2 gloads)
  const size_t gs0 = (size_t)(wid * 16 + (lane >> 3)) * K_DIM +
                     (((lane & 7) ^ (lane >> 3)) << 3);
  const size_t gs1 = gs0 + (size_t)8 * K_DIM;
  const int ld0 = wid * 2048 + lane * 16;         // LDS byte offsets (linear)
  const int ld1 = ld0 + 1024;
  auto stage = [&](const unsigned short* g, unsigned short* l) {
    gload_lds16(g + gs0, reinterpret_cast<char*>(l) + ld0);
    gload_lds16(g + gs1, reinterpret_cast<char*>(l) + ld1);
  };

  // read invariants (byte offsets; XOR swizzle with loop-invariant key)
  const int inv = (ln & 7) << 4;
  const int c0 = (kh * 16) ^ inv;                 // kk0 column
  const int c1 = (64 + kh * 16) ^ inv;            // kk1 column
  const int arow = wr * 128 + ln;
  const int brow = wc * 64 + ln;

  frag_cd acc[8][4] = {};
  frag_ab Af0[4], Af1[4], Bf0[4], Bf1[4];

  // ---- prologue: stage A(0), B(0); drain; barrier ----
  stage(Ag, As0);
  stage(Ag + 128 * K_DIM, As0 + HALFT);
  stage(Bg, Bs0);
  stage(Bg + 128 * K_DIM, Bs0 + HALFT);
  asm volatile("s_waitcnt vmcnt(0)" ::: "memory");
  SBAR;

  // ---- main loop: 2 K-tiles per iter, static buffers, 1 barrier/tile ----
  for (int u = 0; u < 15; ++u) {
    const int e = 2 * u;
    TILE_BODY(As0, Bs0, As1, Bs1, e, 1, 1);
    TILE_BODY(As1, Bs1, As0, Bs0, e + 1, 1, 1);
  }
  // t=30: stage A/B(31); t=31: pure compute, no trailing barrier
  TILE_BODY(As0, Bs0, As1, Bs1, 30, 1, 1);
  TILE_BODY(As1, Bs1, As0, Bs0, 31, 0, 0);

  // ---- fused LSTM epilogue: n-frag == gate, h = bn*64 + wc*16 + ln ----
  const int hcol = bn * 64 + wc * 16 + ln;
  const float bfv = b_f[hcol], biv = b_i[hcol], bov = b_o[hcol], bgv = b_g[hcol];
  const int row_base = bm * 256 + wr * 128 + kh * 4;
#pragma unroll
  for (int mi = 0; mi < 8; ++mi) {
#pragma unroll
    for (int j = 0; j < 4; ++j) {
      const int row = row_base + mi * 16 + j;
      float fp = acc[mi][0][j] + bfv;
      float ip = acc[mi][1][j] + biv;
      float op = acc[mi][2][j] + bov;
      float gp = acc[mi][3][j] + bgv;
      float ft = fast_sigmoid(fp);
      float it = fast_sigmoid(ip);
      float ot = fast_sigmoid(op);
      float gt = fast_tanh(gp);
      float cold = cx[(size_t)row * H_DIM + hcol];
      float ct = ft * cold + it * gt;
      float ht = ot * fast_tanh(ct);
      out[(size_t)row * H_DIM + hcol] = ht;
      out[BH + (size_t)row * H_DIM + hcol] = ct;
    }
  }
}

extern "C" void kernel_launch(void* const* d_in, const int* in_sizes, int n_in,
                              void* d_out, int out_size, void* d_ws, size_t ws_size,
                              hipStream_t stream) {
  const float* xt   = (const float*)d_in[0];
  const float* cxp  = (const float*)d_in[1];
  const float* hx   = (const float*)d_in[2];
  const float* w_fg = (const float*)d_in[3];
  const float* w_ig = (const float*)d_in[4];
  const float* w_og = (const float*)d_in[5];
  const float* w_ci = (const float*)d_in[6];
  const float* r_fg = (const float*)d_in[7];
  const float* r_ig = (const float*)d_in[8];
  const float* r_og = (const float*)d_in[9];
  const float* r_ci = (const float*)d_in[10];
  const float* b_fg = (const float*)d_in[11];
  const float* b_ig = (const float*)d_in[12];
  const float* b_og = (const float*)d_in[13];
  const float* b_ci = (const float*)d_in[14];

  unsigned short* Abf = (unsigned short*)d_ws;                // 33.5 MB
  unsigned short* Bbf = Abf + (size_t)B_DIM * K_DIM;          // 16.8 MB
  float* out = (float*)d_out;

  convert_A_kernel<<<dim3(B_DIM * K_DIM / 4 / 256), dim3(256), 0, stream>>>(
      xt, hx, Abf);
  convert_B_kernel<<<dim3(N_DIM * K_DIM / 4 / 256), dim3(256), 0, stream>>>(
      w_fg, w_ig, w_og, w_ci, r_fg, r_ig, r_og, r_ci, Bbf);
  lstm_gemm_kernel<<<dim3((B_DIM / 256) * (N_DIM / 256)), dim3(512),
                     131072, stream>>>(
      Abf, Bbf, cxp, b_fg, b_ig, b_og, b_ci, out);
}